// Round 14
// baseline (32.470 us; speedup 1.0000x reference)
//
#include <hip/hip_runtime.h>
#include <math.h>

// Problem constants
#define Dq 512
#define Vq 50257
#define Kq 100
#define KP 112              // K padded to 7*16
#define NORM_TERM 10.8249051f   // log(50257)
#define LOGK 4.6051702f         // log(100)
#define NBLK 1024           // 512 position-tiles x 2 K-halves
#define DT_STRIDE 3584      // nBT: KP*32 elems per d-chunk slab (7KB, non-pow2)

typedef __attribute__((ext_vector_type(8))) short short8;
typedef __attribute__((ext_vector_type(4))) float floatx4;
typedef __attribute__((ext_vector_type(4))) unsigned short ushort4v;
typedef __attribute__((ext_vector_type(8))) unsigned short ushort8v;

__device__ __forceinline__ unsigned short f2bf(float f) {
    union { float f; unsigned u; } v; v.f = f;
    unsigned r = v.u + 0x7FFFu + ((v.u >> 16) & 1u);   // RNE
    return (unsigned short)(r >> 16);
}

__device__ __forceinline__ short8 cvt8(floatx4 a, floatx4 b) {
    short8 o;
    o[0] = (short)f2bf(a.x); o[1] = (short)f2bf(a.y);
    o[2] = (short)f2bf(a.z); o[3] = (short)f2bf(a.w);
    o[4] = (short)f2bf(b.x); o[5] = (short)f2bf(b.y);
    o[6] = (short)f2bf(b.z); o[7] = (short)f2bf(b.w);
    return o;
}

__device__ __forceinline__ float dot4(floatx4 a, floatx4 b) {
    return a.x*b.x + a.y*b.y + a.z*b.z + a.w*b.w;
}

__device__ __forceinline__ float log_sigmoid(float x) {
    return fminf(x, 0.f) - __logf(1.f + __expf(-fabsf(x)));
}

// Gather + convert noise rows to bf16, TRANSPOSED chunk-major layout
// (R8 win): element (k, d) at nBT[(d>>5)*DT_STRIDE + k*32 + (d&31)].
// Block 0 also zeroes out[64] for nce_main's atomic accumulation.
__global__ void prep_noise(const float* __restrict__ emb_w,
                           const float* __restrict__ emb_b,
                           const float* __restrict__ lpn,
                           const int* __restrict__ ns,
                           unsigned short* __restrict__ nBT,
                           float* __restrict__ nAdj,
                           float* __restrict__ out) {
    int k = blockIdx.x;     // 0..111
    int t = threadIdx.x;    // 0..127; d = t*4 .. t*4+3
    size_t off = (size_t)(t >> 3) * DT_STRIDE + k * 32 + (t & 7) * 4;
    if (k < Kq) {
        int row = ns[k];
        floatx4 v = ((const floatx4*)(emb_w + (size_t)row * Dq))[t];
        ushort4v o;
        o.x = f2bf(v.x); o.y = f2bf(v.y); o.z = f2bf(v.z); o.w = f2bf(v.w);
        *(ushort4v*)(nBT + off) = o;
        if (t == 0) nAdj[k] = emb_b[row] - NORM_TERM - lpn[row] - LOGK;
    } else {
        ushort4v z; z.x = 0; z.y = 0; z.z = 0; z.w = 0;
        *(ushort4v*)(nBT + off) = z;
        if (t == 0) nAdj[k] = 0.f;
    }
    if (k == 0 && t < 64) out[t] = 0.f;
}

// GENERATION-PIPELINED version: 1024 blocks (2x resident capacity) so
// while resident blocks compute, queued blocks stage -> the chip-wide
// stage burst and compute phase overlap across block generations.
// Pair p=bid>>1 owns 32 positions; half h=bid&1 splits K:
//   h=0: k-tiles 0..3   (8 waves: w&3 = k-tile, w>>2 = 16-row half)
//   h=1: k-tiles 4..6   (waves 0-2 / 4-6) + target terms (waves 3,7)
// Both halves stage all 32 input rows to their own LDS (input read 2x,
// L3-warm); only h=1 gathers target rows / computes tdot (lighter h=0
// blocks desync the generations). Per-wave: 1 acc, 16 MFMAs.
__global__ __launch_bounds__(512, 4) void nce_main(
    const float* __restrict__ input,     // [16384][512]
    const float* __restrict__ emb_w,     // [V][512]
    const float* __restrict__ emb_b,     // [V]
    const float* __restrict__ lpn,       // [V]
    const int* __restrict__ target,      // [16384]
    const unsigned short* __restrict__ nBT,  // noise, chunk-major bf16
    const float* __restrict__ nAdj,          // [112]
    float* __restrict__ out)                 // [64] accumulated
{
    __shared__ unsigned short A_lds[32 * 512];  // byte: row*1024 + (2c ^ ((row&7)<<4))
    __shared__ float tdot[32];
    __shared__ float blocksum[8];

    int tid  = threadIdx.x;
    int lane = tid & 63;
    int w    = tid >> 6;            // 0..7
    int h    = (int)blockIdx.x & 1;
    int pos0 = ((int)blockIdx.x >> 1) * 32;
    int r16  = lane & 15;
    int g4   = lane >> 4;

    // ---- Stage: 4 rows/wave; full-row 2KB bursts; h=1 also target dots ----
#pragma unroll
    for (int j = 0; j < 4; ++j) {
        int row = w * 4 + j;                         // 0..31
        const float* src = input + (size_t)(pos0 + row) * Dq + lane * 8;
        floatx4 x0 = *(const floatx4*)(src);
        floatx4 x1 = *(const floatx4*)(src + 4);
        if (h) {
            int tg = target[pos0 + row];             // wave-uniform -> scalar
            const float* tsrc = emb_w + (size_t)tg * Dq + lane * 8;
            floatx4 t0 = *(const floatx4*)(tsrc);
            floatx4 t1 = *(const floatx4*)(tsrc + 4);
            float s = dot4(x0, t0) + dot4(x1, t1);
#pragma unroll
            for (int off = 32; off >= 1; off >>= 1)
                s += __shfl_xor(s, off);
            if (lane == 0) tdot[row] = s;
        }
        char* base = (char*)A_lds + row * 1024;
        *(ushort8v*)(base + ((lane * 16) ^ ((row & 7) << 4))) = (ushort8v)cvt8(x0, x1);
    }
    __syncthreads();

    float contrib = 0.f;
    int w4 = w & 3;          // k-slot within half
    int rh = w >> 2;         // 16-row half (0: rows 0-15, 1: rows 16-31)

    if (h == 0 || w4 < 3) {
        // ---- Noise k-tile vs one 16-row half: 1 acc, 16 MFMAs ----
        int kt = h * 4 + w4;                         // 0..3 or 4..6
        const char* abase = (const char*)A_lds + (rh * 16 + r16) * 1024;
        int asw = (r16 & 7) << 4;
        const unsigned short* p = nBT + (size_t)kt * 512 + r16 * 32 + g4 * 8;
        floatx4 acc = {0.f, 0.f, 0.f, 0.f};
#pragma unroll
        for (int dt = 0; dt < 16; ++dt) {
            short8 a = *(const short8*)(abase + ((dt * 64 + g4 * 16) ^ asw));
            short8 f = *(const short8*)(p + (size_t)dt * DT_STRIDE);
            acc = __builtin_amdgcn_mfma_f32_16x16x32_bf16(a, f, acc, 0, 0, 0);
        }
        int k = kt * 16 + r16;
        if (k < Kq) {
            float adj = nAdj[k];
#pragma unroll
            for (int r = 0; r < 4; ++r)
                contrib += log_sigmoid(-(acc[r] + adj));
        }
    } else {
        // ---- Target epilogue (h=1, waves 3/7): 16 positions each ----
        if (g4 == 0) {
            int p32 = rh * 16 + r16;                 // 0..31
            int tg = target[pos0 + p32];
            float xt = tdot[p32] + emb_b[tg] - NORM_TERM - lpn[tg] - LOGK;
            contrib += log_sigmoid(xt);
        }
    }

#pragma unroll
    for (int off = 32; off >= 1; off >>= 1)
        contrib += __shfl_xor(contrib, off);
    if (lane == 0) blocksum[w] = contrib;
    __syncthreads();

    // ---- One atomic per block (16 per out address, 1024 total) ----
    if (tid == 0) {
        float s = 0.f;
#pragma unroll
        for (int i = 0; i < 8; ++i) s += blocksum[i];
        atomicAdd(&out[blockIdx.x >> 4], s);         // batch = pos0/256
    }
}

extern "C" void kernel_launch(void* const* d_in, const int* in_sizes, int n_in,
                              void* d_out, int out_size, void* d_ws, size_t ws_size,
                              hipStream_t stream) {
    const float* input = (const float*)d_in[0];
    const float* emb_w = (const float*)d_in[1];
    const float* emb_b = (const float*)d_in[2];
    const float* lpn   = (const float*)d_in[3];
    const int*   tgt   = (const int*)d_in[4];
    const int*   ns    = (const int*)d_in[5];
    float* out = (float*)d_out;

    // ws layout: [0,114688) nBT bf16; [114688,115200) nAdj(+pad).
    unsigned short* nBT = (unsigned short*)d_ws;
    float* nAdj         = (float*)((char*)d_ws + (size_t)KP * Dq * 2);

    prep_noise<<<KP, 128, 0, stream>>>(emb_w, emb_b, lpn, ns, nBT, nAdj, out);
    nce_main<<<NBLK, 512, 0, stream>>>(input, emb_w, emb_b, lpn, tgt,
                                       nBT, nAdj, out);
}

// Round 15
// 27.352 us; speedup vs baseline: 1.1871x; 1.1871x over previous
//
#include <hip/hip_runtime.h>
#include <math.h>

// Problem constants
#define Dq 512
#define Vq 50257
#define Kq 100
#define KP 112              // K padded to 7*16
#define NORM_TERM 10.8249051f   // log(50257)
#define LOGK 4.6051702f         // log(100)
#define NBLK 512            // 16384 positions / 32 per block
#define DT_STRIDE 3584      // nBT: KP*32 elems per d-chunk slab (7KB, non-pow2)

typedef __attribute__((ext_vector_type(8))) short short8;
typedef __attribute__((ext_vector_type(4))) float floatx4;
typedef __attribute__((ext_vector_type(4))) unsigned short ushort4v;
typedef __attribute__((ext_vector_type(8))) unsigned short ushort8v;

__device__ __forceinline__ unsigned short f2bf(float f) {
    union { float f; unsigned u; } v; v.f = f;
    unsigned r = v.u + 0x7FFFu + ((v.u >> 16) & 1u);   // RNE
    return (unsigned short)(r >> 16);
}

__device__ __forceinline__ short8 cvt8(floatx4 a, floatx4 b) {
    short8 o;
    o[0] = (short)f2bf(a.x); o[1] = (short)f2bf(a.y);
    o[2] = (short)f2bf(a.z); o[3] = (short)f2bf(a.w);
    o[4] = (short)f2bf(b.x); o[5] = (short)f2bf(b.y);
    o[6] = (short)f2bf(b.z); o[7] = (short)f2bf(b.w);
    return o;
}

__device__ __forceinline__ float dot4(floatx4 a, floatx4 b) {
    return a.x*b.x + a.y*b.y + a.z*b.z + a.w*b.w;
}

__device__ __forceinline__ float log_sigmoid(float x) {
    return fminf(x, 0.f) - __logf(1.f + __expf(-fabsf(x)));
}

// Gather + convert noise rows to bf16, TRANSPOSED chunk-major (R8 win):
// element (k, d) at nBT[(d>>5)*DT_STRIDE + k*32 + (d&31)]. Block 0 also
// zeroes out[64] for nce_main's atomic accumulation.
__global__ void prep_noise(const float* __restrict__ emb_w,
                           const float* __restrict__ emb_b,
                           const float* __restrict__ lpn,
                           const int* __restrict__ ns,
                           unsigned short* __restrict__ nBT,
                           float* __restrict__ nAdj,
                           float* __restrict__ out) {
    int k = blockIdx.x;     // 0..111
    int t = threadIdx.x;    // 0..127; d = t*4 .. t*4+3
    size_t off = (size_t)(t >> 3) * DT_STRIDE + k * 32 + (t & 7) * 4;
    if (k < Kq) {
        int row = ns[k];
        floatx4 v = ((const floatx4*)(emb_w + (size_t)row * Dq))[t];
        ushort4v o;
        o.x = f2bf(v.x); o.y = f2bf(v.y); o.z = f2bf(v.z); o.w = f2bf(v.w);
        *(ushort4v*)(nBT + off) = o;
        if (t == 0) nAdj[k] = emb_b[row] - NORM_TERM - lpn[row] - LOGK;
    } else {
        ushort4v z; z.x = 0; z.y = 0; z.z = 0; z.w = 0;
        *(ushort4v*)(nBT + off) = z;
        if (t == 0) nAdj[k] = 0.f;
    }
    if (k == 0 && t < 64) out[t] = 0.f;
}

// Intra-block software pipeline (traffic-free overlap):
//  A: stage rows 0-15 (wave w: rows 2w,2w+1; input+target 2KB bursts,
//     fp32 dot -> tdot, input -> LDS bf16 swizzled). barrier.
//  B: issue row 16+w loads -> 8 MFMAs (k-tile w, rows 0-15, dt 0-7)
//     -> consume (dot + LDS write).          [stage hidden under MFMA]
//  C: same for row 24+w with dt 8-15. barrier.
//  D: 16 MFMAs (rows 16-31) + wave-7 target epilogue; blocksum + atomic.
__global__ __launch_bounds__(512, 4) void nce_main(
    const float* __restrict__ input,     // [16384][512]
    const float* __restrict__ emb_w,     // [V][512]
    const float* __restrict__ emb_b,     // [V]
    const float* __restrict__ lpn,       // [V]
    const int* __restrict__ target,      // [16384]
    const unsigned short* __restrict__ nBT,  // noise, chunk-major bf16
    const float* __restrict__ nAdj,          // [112]
    float* __restrict__ out)                 // [64] accumulated
{
    __shared__ unsigned short A_lds[32 * 512];  // byte: row*1024 + (2c ^ ((row&7)<<4))
    __shared__ float tdot[32];
    __shared__ float blocksum[8];

    int tid  = threadIdx.x;
    int lane = tid & 63;
    int w    = tid >> 6;            // 0..7
    int pos0 = (int)blockIdx.x * 32;
    int r16  = lane & 15;
    int g4   = lane >> 4;

    // ---- Phase A: stage rows 0..15 (wave w: rows 2w, 2w+1) ----
#pragma unroll
    for (int j = 0; j < 2; ++j) {
        int row = w * 2 + j;
        const float* src = input + (size_t)(pos0 + row) * Dq + lane * 8;
        int tg = target[pos0 + row];
        const float* tsrc = emb_w + (size_t)tg * Dq + lane * 8;
        floatx4 x0 = *(const floatx4*)(src);
        floatx4 x1 = *(const floatx4*)(src + 4);
        floatx4 t0 = *(const floatx4*)(tsrc);
        floatx4 t1 = *(const floatx4*)(tsrc + 4);
        float s = dot4(x0, t0) + dot4(x1, t1);
#pragma unroll
        for (int off = 32; off >= 1; off >>= 1)
            s += __shfl_xor(s, off);
        if (lane == 0) tdot[row] = s;
        char* base = (char*)A_lds + row * 1024;
        *(ushort8v*)(base + ((lane * 16) ^ ((row & 7) << 4))) = (ushort8v)cvt8(x0, x1);
    }
    __syncthreads();

    const char* a0base = (const char*)A_lds + r16 * 1024;          // rows 0-15
    const char* a1base = a0base + 16 * 1024;                       // rows 16-31
    int asw = (r16 & 7) << 4;
    const unsigned short* p = nBT + (size_t)w * 512 + r16 * 32 + g4 * 8;
    floatx4 acc0 = {0.f, 0.f, 0.f, 0.f};
    floatx4 acc1 = {0.f, 0.f, 0.f, 0.f};

    // ---- Phases B, C: stage rows 16+w / 24+w under acc0's MFMAs ----
#pragma unroll
    for (int ph = 0; ph < 2; ++ph) {
        int row = 16 + ph * 8 + w;                   // 16..23 then 24..31
        // issue-early: 16 loads in flight across the MFMA cluster
        const float* src = input + (size_t)(pos0 + row) * Dq + lane * 8;
        int tg = target[pos0 + row];
        const float* tsrc = emb_w + (size_t)tg * Dq + lane * 8;
        floatx4 x0 = *(const floatx4*)(src);
        floatx4 x1 = *(const floatx4*)(src + 4);
        floatx4 t0 = *(const floatx4*)(tsrc);
        floatx4 t1 = *(const floatx4*)(tsrc + 4);
        // 8 MFMAs on the already-staged half (dt = ph*8 .. ph*8+7)
        if (w < 7) {
#pragma unroll
            for (int d = 0; d < 8; ++d) {
                int dt = ph * 8 + d;
                short8 a = *(const short8*)(a0base + ((dt * 64 + g4 * 16) ^ asw));
                short8 f = *(const short8*)(p + (size_t)dt * DT_STRIDE);
                acc0 = __builtin_amdgcn_mfma_f32_16x16x32_bf16(a, f, acc0, 0, 0, 0);
            }
        }
        // consume-late
        float s = dot4(x0, t0) + dot4(x1, t1);
#pragma unroll
        for (int off = 32; off >= 1; off >>= 1)
            s += __shfl_xor(s, off);
        if (lane == 0) tdot[row] = s;
        char* base = (char*)A_lds + row * 1024;
        *(ushort8v*)(base + ((lane * 16) ^ ((row & 7) << 4))) = (ushort8v)cvt8(x0, x1);
    }
    __syncthreads();

    // ---- Phase D: rows 16-31 MFMAs; wave 7: target epilogue ----
    float contrib = 0.f;
    if (w < 7) {
#pragma unroll
        for (int dt = 0; dt < 16; ++dt) {
            short8 a = *(const short8*)(a1base + ((dt * 64 + g4 * 16) ^ asw));
            short8 f = *(const short8*)(p + (size_t)dt * DT_STRIDE);
            acc1 = __builtin_amdgcn_mfma_f32_16x16x32_bf16(a, f, acc1, 0, 0, 0);
        }
        int k = w * 16 + r16;
        if (k < Kq) {
            float adj = nAdj[k];
#pragma unroll
            for (int r = 0; r < 4; ++r) {
                contrib += log_sigmoid(-(acc0[r] + adj));
                contrib += log_sigmoid(-(acc1[r] + adj));
            }
        }
    } else {
        if (g4 < 2) {
            int p32 = g4 * 16 + r16;                 // 0..31
            int tg = target[pos0 + p32];
            float xt = tdot[p32] + emb_b[tg] - NORM_TERM - lpn[tg] - LOGK;
            contrib += log_sigmoid(xt);
        }
    }

#pragma unroll
    for (int off = 32; off >= 1; off >>= 1)
        contrib += __shfl_xor(contrib, off);
    if (lane == 0) blocksum[w] = contrib;
    __syncthreads();

    // ---- One atomic per block (8 per out address, 512 total) ----
    if (tid == 0) {
        float s = 0.f;
#pragma unroll
        for (int i = 0; i < 8; ++i) s += blocksum[i];
        atomicAdd(&out[blockIdx.x >> 3], s);         // batch = pos0/256
    }
}

extern "C" void kernel_launch(void* const* d_in, const int* in_sizes, int n_in,
                              void* d_out, int out_size, void* d_ws, size_t ws_size,
                              hipStream_t stream) {
    const float* input = (const float*)d_in[0];
    const float* emb_w = (const float*)d_in[1];
    const float* emb_b = (const float*)d_in[2];
    const float* lpn   = (const float*)d_in[3];
    const int*   tgt   = (const int*)d_in[4];
    const int*   ns    = (const int*)d_in[5];
    float* out = (float*)d_out;

    // ws layout: [0,114688) nBT bf16; [114688,115200) nAdj(+pad).
    unsigned short* nBT = (unsigned short*)d_ws;
    float* nAdj         = (float*)((char*)d_ws + (size_t)KP * Dq * 2);

    prep_noise<<<KP, 128, 0, stream>>>(emb_w, emb_b, lpn, ns, nBT, nAdj, out);
    nce_main<<<NBLK, 512, 0, stream>>>(input, emb_w, emb_b, lpn, tgt,
                                       nBT, nAdj, out);
}